// Round 9
// baseline (65.987 us; speedup 1.0000x reference)
//
#include <hip/hip_runtime.h>

#define NNODES 128
#define BATCH  32768
#define BLOCK  256                          // 4 waves
#define ROWS_PER_CHUNK 8                    // 4 waves x 2 rows
#define NCHUNKS (BATCH / ROWS_PER_CHUNK)    // 4096
#define GRID   1024                         // 4 chunks/block

typedef __fp16 half2_t __attribute__((ext_vector_type(2)));

__device__ __forceinline__ half2_t h2_(unsigned u) {
    union { unsigned u; half2_t h; } cv; cv.u = u; return cv.h;
}
__device__ __forceinline__ unsigned pk_(float a, float b) {
    union { half2_t h; unsigned u; } cv;
    cv.h = __builtin_amdgcn_cvt_pkrtz(a, b);   // v_cvt_pkrtz_f16_f32
    return cv.u;
}

__device__ __forceinline__ float sigmoidf_(float z) {
    return 1.0f / (1.0f + __expf(-z));
}

__device__ __forceinline__ float clipf_(float v) {
    return fminf(fmaxf(v, -100.0f), 100.0f);
}

// Per-node epilogue: 8 clipped states + node_input + params -> 8 derivatives.
__device__ __forceinline__ void node_update(const float* xs8, float ni,
                                            const float* gi, const float* invTi,
                                            float sci, float Ri, float* f8) {
    float S0 = sigmoidf_(Ri * xs8[0]) - 0.5f;
    float S2 = sigmoidf_(Ri * xs8[2]) - 0.5f;
    float S4 = sigmoidf_(Ri * xs8[4]) - 0.5f;
    float S6 = sigmoidf_(Ri * xs8[6]) - 0.5f;
    float u1 = ni - gi[0] * S0 - gi[1] * S2 - gi[2]  * S4;
    float u3 = ni + gi[7] * S0 - gi[6] * S2 - gi[11] * S4;
    float u5 = ni + gi[4] * S0 + gi[10] * S2 - gi[3] * S4 + gi[5] * S6;
    float u7 = ni - gi[8] * S4 - gi[9] * S6;
    f8[0] = sci * xs8[1];
    f8[1] = sci * (u1 - 2.0f * xs8[1] - xs8[0] * invTi[0]) * invTi[0];
    f8[2] = sci * xs8[3];
    f8[3] = sci * (u3 - 2.0f * xs8[3] - xs8[2] * invTi[1]) * invTi[1];
    f8[4] = sci * xs8[5];
    f8[5] = sci * (u5 - 2.0f * xs8[5] - xs8[4] * invTi[2]) * invTi[2];
    f8[6] = sci * xs8[7];
    f8[7] = sci * (u7 - 2.0f * xs8[7] - xs8[6] * invTi[3]) * invTi[3];
}

__global__ __launch_bounds__(BLOCK, 2)
void cmc_kernel(const float* __restrict__ x,
                const float* __restrict__ C,
                const float* __restrict__ G,
                const float* __restrict__ T,
                const float* __restrict__ adap,
                const float* __restrict__ R,
                float* __restrict__ out)
{
    // ct4[jp2*64 + p] (16B record): f16-packed C (diag zeroed), NO transpose:
    //   .x = {C[2p][4jp2+0], C[2p][4jp2+1]}   (half2, j-consecutive pair)
    //   .y = {C[2p][4jp2+2], C[2p][4jp2+3]}
    //   .z/.w = same for row 2p+1.
    // Reads (uniform jp2, lane=p): 64 lanes x 16B = contiguous 1024B -> conflict-free
    // (same pattern R5 verified at SQ_LDS_BANK_CONFLICT==0). Staging writes: same.
    __shared__ uint4 ct4[32 * 64];                       // 32 KB
    __shared__ __align__(16) uint2 m2a[4][64];           //  2 KB: [wave][jp] = {row0 pk, row1 pk}

    const int tid  = threadIdx.x;
    const int lane = tid & 63;
    const int w    = tid >> 6;            // wave 0..3
    const int nA   = 2 * lane;            // this lane's nodes: nA, nA+1

    // ---- stage ct once per block: pack f16 pairs along j (no transpose) ----
    {
        const int p   = tid & 63;          // node pair (rows 2p, 2p+1)
        const int seg = tid >> 6;          // col window seg*32 .. +32
        const int c0  = seg * 32;
        const int r0i = 2 * p, r1i = 2 * p + 1;
        float4 qv0[8], qv1[8];
        #pragma unroll
        for (int q = 0; q < 8; ++q) {
            qv0[q] = *reinterpret_cast<const float4*>(C + (size_t)r0i * NNODES + c0 + 4 * q);
            qv1[q] = *reinterpret_cast<const float4*>(C + (size_t)r1i * NNODES + c0 + 4 * q);
        }
        #pragma unroll
        for (int q = 0; q < 8; ++q) {
            const int colb = c0 + 4 * q;
            float a0 = (r0i == colb + 0) ? 0.f : qv0[q].x;
            float b0 = (r0i == colb + 1) ? 0.f : qv0[q].y;
            float c0v= (r0i == colb + 2) ? 0.f : qv0[q].z;
            float d0 = (r0i == colb + 3) ? 0.f : qv0[q].w;
            float a1 = (r1i == colb + 0) ? 0.f : qv1[q].x;
            float b1 = (r1i == colb + 1) ? 0.f : qv1[q].y;
            float c1v= (r1i == colb + 2) ? 0.f : qv1[q].z;
            float d1 = (r1i == colb + 3) ? 0.f : qv1[q].w;
            uint4 rec;
            rec.x = pk_(a0, b0); rec.y = pk_(c0v, d0);
            rec.z = pk_(a1, b1); rec.w = pk_(c1v, d1);
            ct4[(seg * 8 + q) * 64 + p] = rec;
        }
    }

    // ---- per-node params (2 nodes/lane) ----
    float g[2][12], invT[2][4], sc[2], Rr[2];
    #pragma unroll
    for (int i = 0; i < 2; ++i) {
        int n = nA + i;
        #pragma unroll
        for (int k = 0; k < 12; ++k) g[i][k] = G[n * 12 + k];
        #pragma unroll
        for (int k = 0; k < 4; ++k) invT[i][k] = 1.0f / T[n * 4 + k];
        sc[i] = 0.1f * sigmoidf_(adap[n]);
        Rr[i] = R[n];
    }

    __syncthreads();   // ct4 visible; ONLY barrier in the kernel

    uint2* m2 = &m2a[w][0];   // wave-private

    for (int chunk = blockIdx.x; chunk < NCHUNKS; chunk += GRID) {
        const int r0 = chunk * ROWS_PER_CHUNK + 2 * w;   // wave's rows: r0, r0+1

        // ---- load + clip x: 2 rows, this lane's 16 columns (own 2 nodes) ----
        float xv[2][16];
        {
            const float4* p0 = reinterpret_cast<const float4*>(x + (size_t)r0 * 1024 + lane * 16);
            const float4* p1 = reinterpret_cast<const float4*>(x + (size_t)(r0 + 1) * 1024 + lane * 16);
            #pragma unroll
            for (int q = 0; q < 4; ++q) {
                float4 v = p0[q];
                xv[0][q * 4 + 0] = clipf_(v.x); xv[0][q * 4 + 1] = clipf_(v.y);
                xv[0][q * 4 + 2] = clipf_(v.z); xv[0][q * 4 + 3] = clipf_(v.w);
            }
            #pragma unroll
            for (int q = 0; q < 4; ++q) {
                float4 v = p1[q];
                xv[1][q * 4 + 0] = clipf_(v.x); xv[1][q * 4 + 1] = clipf_(v.y);
                xv[1][q * 4 + 2] = clipf_(v.z); xv[1][q * 4 + 3] = clipf_(v.w);
            }
        }

        // ---- node means (lane-local), f16-pack -> wave-private LDS ----
        {
            float s00 = 0.f, s01 = 0.f, s10 = 0.f, s11 = 0.f;
            #pragma unroll
            for (int k = 0; k < 8; ++k) {
                s00 += xv[0][k]; s01 += xv[0][8 + k];
                s10 += xv[1][k]; s11 += xv[1][8 + k];
            }
            uint2 mv;
            mv.x = pk_(s00 * 0.125f, s01 * 0.125f);   // row0: {m[nA], m[nA+1]}
            mv.y = pk_(s10 * 0.125f, s11 * 0.125f);   // row1
            m2[lane] = mv;                            // 8B stride: 2-way, free
        }
        // same-wave write->read: ordered by lgkmcnt, no barrier needed

        // ---- node_input via v_dot2_f32_f16 ----
        float acc00 = 0.f, acc01 = 0.f, acc10 = 0.f, acc11 = 0.f;
        #pragma unroll 4
        for (int jp2 = 0; jp2 < 32; ++jp2) {
            uint4 mm = *reinterpret_cast<const uint4*>(&m2[2 * jp2]);  // uniform broadcast
            uint4 ct = ct4[jp2 * 64 + lane];                           // contiguous, free
            acc00 = __builtin_amdgcn_fdot2(h2_(mm.x), h2_(ct.x), acc00, false);
            acc00 = __builtin_amdgcn_fdot2(h2_(mm.z), h2_(ct.y), acc00, false);
            acc01 = __builtin_amdgcn_fdot2(h2_(mm.x), h2_(ct.z), acc01, false);
            acc01 = __builtin_amdgcn_fdot2(h2_(mm.z), h2_(ct.w), acc01, false);
            acc10 = __builtin_amdgcn_fdot2(h2_(mm.y), h2_(ct.x), acc10, false);
            acc10 = __builtin_amdgcn_fdot2(h2_(mm.w), h2_(ct.y), acc10, false);
            acc11 = __builtin_amdgcn_fdot2(h2_(mm.y), h2_(ct.z), acc11, false);
            acc11 = __builtin_amdgcn_fdot2(h2_(mm.w), h2_(ct.w), acc11, false);
        }

        // ---- epilogue + store: 2 rows x 2 nodes ----
        {
            float* o0 = out + (size_t)r0 * 1024 + lane * 16;
            float* o1 = o0 + 1024;
            float f8[8];
            node_update(&xv[0][0], acc00, g[0], invT[0], sc[0], Rr[0], f8);
            *reinterpret_cast<float4*>(o0)      = make_float4(f8[0], f8[1], f8[2], f8[3]);
            *reinterpret_cast<float4*>(o0 + 4)  = make_float4(f8[4], f8[5], f8[6], f8[7]);
            node_update(&xv[0][8], acc01, g[1], invT[1], sc[1], Rr[1], f8);
            *reinterpret_cast<float4*>(o0 + 8)  = make_float4(f8[0], f8[1], f8[2], f8[3]);
            *reinterpret_cast<float4*>(o0 + 12) = make_float4(f8[4], f8[5], f8[6], f8[7]);
            node_update(&xv[1][0], acc10, g[0], invT[0], sc[0], Rr[0], f8);
            *reinterpret_cast<float4*>(o1)      = make_float4(f8[0], f8[1], f8[2], f8[3]);
            *reinterpret_cast<float4*>(o1 + 4)  = make_float4(f8[4], f8[5], f8[6], f8[7]);
            node_update(&xv[1][8], acc11, g[1], invT[1], sc[1], Rr[1], f8);
            *reinterpret_cast<float4*>(o1 + 8)  = make_float4(f8[0], f8[1], f8[2], f8[3]);
            *reinterpret_cast<float4*>(o1 + 12) = make_float4(f8[4], f8[5], f8[6], f8[7]);
        }
        // m2 is wave-private: WAR across chunks is same-wave, safe
    }
}

extern "C" void kernel_launch(void* const* d_in, const int* in_sizes, int n_in,
                              void* d_out, int out_size, void* d_ws, size_t ws_size,
                              hipStream_t stream) {
    // setup_inputs order: t, x, node_connectivity, G, T, adaptation, R
    const float* x    = (const float*)d_in[1];
    const float* C    = (const float*)d_in[2];
    const float* G    = (const float*)d_in[3];
    const float* T    = (const float*)d_in[4];
    const float* adap = (const float*)d_in[5];
    const float* R    = (const float*)d_in[6];
    float* out        = (float*)d_out;

    hipLaunchKernelGGL(cmc_kernel, dim3(GRID), dim3(BLOCK), 0, stream,
                       x, C, G, T, adap, R, out);
}